// Round 10
// baseline (420.693 us; speedup 1.0000x reference)
//
#include <hip/hip_runtime.h>
#include <cfloat>
#include <cmath>

#define M     16384
#define K     4096
#define E     64
#define TOPK  8
#define GAP_THRESH 1e-3f

#define CH    32               // k per chunk
#define RBK   32               // rows per block
#define NCH   (K / CH)         // 128

typedef __attribute__((ext_vector_type(8))) short bf16x8;
typedef __attribute__((ext_vector_type(4))) float f32x4;

// ws layout: [WdT 2MB][Wh 512KB][Wl 512KB][count 256B][list 64KB]

__device__ __forceinline__ short f2bf(float f) {           // RNE fp32->bf16
    unsigned u = __builtin_bit_cast(unsigned, f);
    u += 0x7FFFu + ((u >> 16) & 1u);
    return (short)(u >> 16);
}
__device__ __forceinline__ float bf2f(short h) {           // exact widen
    unsigned u = ((unsigned)(unsigned short)h) << 16;
    return __builtin_bit_cast(float, u);
}

__global__ __launch_bounds__(256) void prep_kernel(const float* __restrict__ W,
                                                   short* __restrict__ Wh,
                                                   short* __restrict__ Wl,
                                                   double* __restrict__ WdT,
                                                   int* __restrict__ count) {
    int t = blockIdx.x * 256 + threadIdx.x;   // t = e*4096 + k
    float w = W[t];
    short h = f2bf(w);
    Wh[t] = h;
    Wl[t] = f2bf(w - bf2f(h));
    int e = t >> 12, k = t & 4095;
    WdT[(size_t)k * E + e] = (double)w;
    if (t == 0) *count = 0;
}

__device__ __forceinline__ void gload_lds16(const void* g, void* l) {
    __builtin_amdgcn_global_load_lds(
        (const __attribute__((address_space(1))) unsigned int*)g,
        (__attribute__((address_space(3))) unsigned int*)l, 16, 0, 0);
}

// ---------------------------------------------------------------------------
// MFMA gate: 3-pass split-bf16 (xh*Wh + xh*Wl + xl*Wh), fp32 accum.
// Block = 128 thr (2 waves), 32 rows x 64 experts x full K.  Grid 512.
// Wave tile: 16 rows x 64 e = 4 MFMA 16x16x32 tiles; 12 MFMA per k32.
// W staged hi/lo bf16 via gload_lds (source XOR-swizzled slot s^((e>>1)&3),
// linear dest per rule #21); x reg-staged -> cvt hi/lo -> swizzled ds_write
// (write-side swizzle s^((row>>1)&3)); both frag reads land at LDS BW floor.
// Epilogue: acc -> LDS logit tile -> proven top-9/ballot/softmax/flag.
// ---------------------------------------------------------------------------
__global__ __launch_bounds__(128) void gate_kernel(
    const float* __restrict__ x,
    const short* __restrict__ Wh,
    const short* __restrict__ Wl,
    const float* __restrict__ b,
    float* __restrict__ outp,    // [M,64]
    float* __restrict__ outi,    // [M,8]
    int*   __restrict__ count,
    int*   __restrict__ list)
{
    __shared__ short lxh[2][RBK * CH];   // [row][k] 64B rows, swizzled   4KB
    __shared__ short lxl[2][RBK * CH];   //                              4KB
    __shared__ short lwh[2][E * CH];     // [e][k] 64B rows, swizzled    8KB
    __shared__ short lwl[2][E * CH];     //                              8KB
    __shared__ float llog[RBK * E];      // logit tile                   8KB

    const int t    = threadIdx.x;
    const int l    = t & 63;
    const int wv   = t >> 6;
    const int row0 = blockIdx.x * RBK;

    // ---- x staging: thread owns (row = t&31, k-granule = t>>5) ------------
    const int srow = t & 31;
    const int skg  = t >> 5;                                 // 0..3
    const float* gx = x + (size_t)(row0 + srow) * K + skg * 8;
    const int xwoff = srow * CH + ((skg ^ ((srow >> 1) & 3)) * 8);

    // ---- W staging source pointers (pre-swizzled global, linear LDS dest) -
    const short* gwh[2];
    const short* gwl[2];
#pragma unroll
    for (int i = 0; i < 2; ++i) {
        const int e = wv * 32 + i * 16 + (l >> 2);
        const int g = (l & 3) ^ ((e >> 1) & 3);
        gwh[i] = Wh + (size_t)e * K + g * 8;
        gwl[i] = Wl + (size_t)e * K + g * 8;
    }

#define STAGEW(bb, koff) do {                                          \
        _Pragma("unroll")                                              \
        for (int i_ = 0; i_ < 2; ++i_) {                               \
            gload_lds16(gwh[i_] + (koff), &lwh[bb][(wv * 2 + i_) * 512]); \
            gload_lds16(gwl[i_] + (koff), &lwl[bb][(wv * 2 + i_) * 512]); \
        }                                                              \
    } while (0)

#define CVTWRITE(bb, va, vb) do {                                      \
        float vv[8] = {va.x, va.y, va.z, va.w, vb.x, vb.y, vb.z, vb.w};\
        bf16x8 vh, vl;                                                 \
        _Pragma("unroll")                                              \
        for (int j_ = 0; j_ < 8; ++j_) {                               \
            short h_ = f2bf(vv[j_]);                                   \
            vh[j_] = h_;                                               \
            vl[j_] = f2bf(vv[j_] - bf2f(h_));                          \
        }                                                              \
        *(bf16x8*)&lxh[bb][xwoff] = vh;                                \
        *(bf16x8*)&lxl[bb][xwoff] = vl;                                \
    } while (0)

    // ---- frag read offsets (compile-time-ish, swizzled) -------------------
    const int arow = wv * 16 + (l & 15);
    const int aoff = arow * CH + (((l >> 4) ^ ((arow >> 1) & 3)) * 8);
    int boff[4];
#pragma unroll
    for (int et = 0; et < 4; ++et) {
        const int e = et * 16 + (l & 15);
        boff[et] = e * CH + (((l >> 4) ^ ((e >> 1) & 3)) * 8);
    }

    f32x4 acc[4] = {{0,0,0,0},{0,0,0,0},{0,0,0,0},{0,0,0,0}};

#define COMPUTE(bb) do {                                               \
        bf16x8 ah = *(const bf16x8*)&lxh[bb][aoff];                    \
        bf16x8 al = *(const bf16x8*)&lxl[bb][aoff];                    \
        _Pragma("unroll")                                              \
        for (int et = 0; et < 4; ++et) {                               \
            bf16x8 bh = *(const bf16x8*)&lwh[bb][boff[et]];            \
            bf16x8 bl = *(const bf16x8*)&lwl[bb][boff[et]];            \
            acc[et] = __builtin_amdgcn_mfma_f32_16x16x32_bf16(ah, bh, acc[et], 0, 0, 0); \
            acc[et] = __builtin_amdgcn_mfma_f32_16x16x32_bf16(ah, bl, acc[et], 0, 0, 0); \
            acc[et] = __builtin_amdgcn_mfma_f32_16x16x32_bf16(al, bh, acc[et], 0, 0, 0); \
        }                                                              \
    } while (0)

    // ---- prologue: chunk 0 ------------------------------------------------
    {
        float4 pa = *reinterpret_cast<const float4*>(gx);
        float4 pb = *reinterpret_cast<const float4*>(gx + 4);
        STAGEW(0, 0);
        CVTWRITE(0, pa, pb);
    }
    __syncthreads();

    int buf = 0;
    for (int c = 0; c < NCH; ++c) {
        float4 pa, pb;
        if (c + 1 < NCH) {                       // issue next-chunk loads
            pa = *reinterpret_cast<const float4*>(gx + (c + 1) * CH);
            pb = *reinterpret_cast<const float4*>(gx + (c + 1) * CH + 4);
            STAGEW(buf ^ 1, (c + 1) * CH);
        }
        COMPUTE(buf);                            // MFMA hides load latency
        if (c + 1 < NCH) CVTWRITE(buf ^ 1, pa, pb);
        __syncthreads();
        buf ^= 1;
    }
#undef COMPUTE
#undef CVTWRITE
#undef STAGEW

    // ---- acc -> LDS logit tile -------------------------------------------
#pragma unroll
    for (int et = 0; et < 4; ++et)
#pragma unroll
        for (int r = 0; r < 4; ++r)
            llog[(wv * 16 + (l >> 4) * 4 + r) * E + et * 16 + (l & 15)] = acc[et][r];
    __syncthreads();

    // ---- fused epilogue: proven top-9 / ballot / softmax / flag ----------
    const float bv = b[l];
    for (int rr = 0; rr < 16; ++rr) {
        const int rloc = wv * 16 + rr;
        const int row  = row0 + rloc;
        const float orig = llog[rloc * E + l] + bv;

        float cur = orig;
        float vals[9];
        float myidxf = 0.0f;
        bool  sel = false;

#pragma unroll
        for (int i = 0; i < 9; ++i) {
            float m = cur;
#pragma unroll
            for (int off = 32; off > 0; off >>= 1)
                m = fmaxf(m, __shfl_xor(m, off, 64));
            unsigned long long msk = __ballot(cur == m);
            int il = __ffsll((long long)msk) - 1;
            vals[i] = m;
            if (l == il) { cur = -FLT_MAX; if (i < TOPK) sel = true; }
            if (i < TOPK && l == i) myidxf = (float)il;
        }

        float ssum = 0.0f;
#pragma unroll
        for (int i = 0; i < TOPK; ++i) ssum += expf(vals[i] - vals[0]);
        float p = sel ? (expf(orig - vals[0]) / ssum) : 0.0f;

        outp[(size_t)row * E + l] = p;
        if (l < TOPK) outi[(size_t)row * TOPK + l] = myidxf;

        float mingap = FLT_MAX;
#pragma unroll
        for (int i = 0; i < 8; ++i) mingap = fminf(mingap, vals[i] - vals[i + 1]);
        if (l == 0 && mingap < GAP_THRESH) {
            int pos = atomicAdd(count, 1);
            if (pos < M) list[pos] = row;
        }
    }
}

// ---------------------------------------------------------------------------
// fp64 rescue, batched: block = 192 thr = 3 waves = 3 rows sharing one WdT
// stream (kills the 2MB-per-row L2 re-read).  Per wave: own x row in LDS
// (coalesced float4 stage), lane = expert, WdT[k][e] coalesced 512B reads.
// ---------------------------------------------------------------------------
__global__ __launch_bounds__(192) void fix_kernel(
    const float*  __restrict__ x,
    const double* __restrict__ WdT,
    const float*  __restrict__ b,
    float* __restrict__ outp,
    float* __restrict__ outi,
    const int* __restrict__ count,
    const int* __restrict__ list)
{
    __shared__ float xs[3][K];      // 48 KB
    const int l   = threadIdx.x & 63;
    const int wv  = threadIdx.x >> 6;
    const int cnt = *count;

    for (int base = blockIdx.x * 3; base < cnt; base += gridDim.x * 3) {
        const int idx = base + wv;
        const int row = (idx < cnt) ? list[idx] : list[cnt - 1];

        const float4* xr4 = reinterpret_cast<const float4*>(x + (size_t)row * K);
#pragma unroll
        for (int j = 0; j < K / 4 / 64; ++j)
            reinterpret_cast<float4*>(xs[wv])[j * 64 + l] = xr4[j * 64 + l];
        // no barrier: each wave reads only its own xs slice

        double a0 = 0.0, a1 = 0.0, a2 = 0.0, a3 = 0.0;
        for (int k = 0; k < K; k += 4) {
            float4 xv = *reinterpret_cast<const float4*>(&xs[wv][k]);
            a0 = fma((double)xv.x, WdT[(size_t)(k + 0) * E + l], a0);
            a1 = fma((double)xv.y, WdT[(size_t)(k + 1) * E + l], a1);
            a2 = fma((double)xv.z, WdT[(size_t)(k + 2) * E + l], a2);
            a3 = fma((double)xv.w, WdT[(size_t)(k + 3) * E + l], a3);
        }
        const double orig = ((a0 + a1) + (a2 + a3)) + (double)b[l];
        double cur = orig;

        double vals[TOPK];
        float  myidxf = 0.0f;
        bool   sel = false;

#pragma unroll
        for (int tt = 0; tt < TOPK; ++tt) {
            double m = cur;
#pragma unroll
            for (int off = 32; off > 0; off >>= 1) {
                double o = __shfl_xor(m, off, 64);
                m = fmax(m, o);
            }
            unsigned long long msk = __ballot(cur == m);
            int il = __ffsll((long long)msk) - 1;
            vals[tt] = m;
            if (l == il) { cur = -DBL_MAX; sel = true; }
            if (l == tt)  myidxf = (float)il;
        }

        double ssum = 0.0;
#pragma unroll
        for (int tt = 0; tt < TOPK; ++tt) ssum += exp(vals[tt] - vals[0]);
        float p = sel ? (float)(exp(orig - vals[0]) / ssum) : 0.0f;

        if (idx < cnt) {
            outp[(size_t)row * E + l] = p;
            if (l < TOPK) outi[(size_t)row * TOPK + l] = myidxf;
        }
        __syncthreads();   // xs slices reused next pass
    }
}

// ---------------------------------------------------------------------------
// Fallback (tiny ws): per-thread-row full fp64 from f32 W.  Correct, slow.
// ---------------------------------------------------------------------------
__global__ __launch_bounds__(64) void fallback_kernel(
    const float* __restrict__ x,
    const float* __restrict__ W,
    const float* __restrict__ b,
    float* __restrict__ outp,
    float* __restrict__ outi)
{
    const int row = blockIdx.x * 64 + threadIdx.x;
    double lg[64];
#pragma unroll
    for (int e = 0; e < 64; ++e) lg[e] = (double)b[e];
    const float* xr = x + (size_t)row * K;
    for (int k = 0; k < K; k += 4) {
        float4 xa = *reinterpret_cast<const float4*>(xr + k);
        double xd[4] = {(double)xa.x, (double)xa.y, (double)xa.z, (double)xa.w};
#pragma unroll
        for (int e = 0; e < 64; ++e) {
            const float* wp = W + (size_t)e * K + k;
            double a = lg[e];
#pragma unroll
            for (int j = 0; j < 4; ++j) a = fma(xd[j], (double)wp[j], a);
            lg[e] = a;
        }
    }
    unsigned long long selm = 0ull;
    double vals[TOPK]; int idx[TOPK];
#pragma unroll
    for (int i = 0; i < TOPK; ++i) {
        double m = -DBL_MAX; int mi = 0;
#pragma unroll
        for (int e = 0; e < 64; ++e) {
            bool gt = !((selm >> e) & 1ull) && (lg[e] > m);
            m = gt ? lg[e] : m; mi = gt ? e : mi;
        }
        vals[i] = m; idx[i] = mi; selm |= (1ull << mi);
    }
    double ssum = 0.0;
#pragma unroll
    for (int i = 0; i < TOPK; ++i) ssum += exp(vals[i] - vals[0]);
    double inv = 1.0 / ssum;
#pragma unroll
    for (int e = 0; e < 64; ++e)
        outp[(size_t)row * E + e] =
            ((selm >> e) & 1ull) ? (float)(exp(lg[e] - vals[0]) * inv) : 0.0f;
#pragma unroll
    for (int i = 0; i < TOPK; ++i)
        outi[(size_t)row * TOPK + i] = (float)idx[i];
}

// ---------------------------------------------------------------------------
extern "C" void kernel_launch(void* const* d_in, const int* in_sizes, int n_in,
                              void* d_out, int out_size, void* d_ws, size_t ws_size,
                              hipStream_t stream) {
    (void)in_sizes; (void)n_in; (void)out_size;
    const float* x = (const float*)d_in[0];
    const float* W = (const float*)d_in[1];
    const float* b = (const float*)d_in[2];

    float* outp = (float*)d_out;
    float* outi = outp + (size_t)M * E;

    const size_t wdt_bytes = sizeof(double) * (size_t)E * K;       // 2 MB
    const size_t wh_off    = wdt_bytes;
    const size_t wl_off    = wh_off + sizeof(short) * (size_t)E * K;  // +512 KB
    const size_t cnt_off   = wl_off + sizeof(short) * (size_t)E * K;  // +512 KB
    const size_t list_off  = cnt_off + 256;
    const size_t need      = list_off + (size_t)M * sizeof(int);

    if (ws_size >= need) {
        double* WdT  = (double*)d_ws;
        short*  Wh   = (short*)((char*)d_ws + wh_off);
        short*  Wl   = (short*)((char*)d_ws + wl_off);
        int*    cnt  = (int*)((char*)d_ws + cnt_off);
        int*    list = (int*)((char*)d_ws + list_off);

        prep_kernel<<<(E * K) / 256, 256, 0, stream>>>(W, Wh, Wl, WdT, cnt);
        gate_kernel<<<M / RBK, 128, 0, stream>>>(x, Wh, Wl, b, outp, outi, cnt, list);
        fix_kernel<<<512, 192, 0, stream>>>(x, WdT, b, outp, outi, cnt, list);
    } else {
        fallback_kernel<<<M / 64, 64, 0, stream>>>(x, W, b, outp, outi);
    }
}

// Round 11
// 277.894 us; speedup vs baseline: 1.5139x; 1.5139x over previous
//
#include <hip/hip_runtime.h>
#include <cfloat>
#include <cmath>

#define M     16384
#define K     4096
#define E     64
#define TOPK  8
#define GAP_THRESH 3e-4f

#define SPLIT 4                 // K-split
#define KPS   (K / SPLIT)       // 1024 k per wave
#define NCH   (KPS / 32)        // 32 chunks of k32

typedef __attribute__((ext_vector_type(8))) short bf16x8;
typedef __attribute__((ext_vector_type(4))) float f32x4;

// ws layout: [WdT 2MB][Wh 512KB][Wl 512KB][count 256B][list 64KB][part 16MB]

__device__ __forceinline__ short f2bf(float f) {           // RNE fp32->bf16
    unsigned u = __builtin_bit_cast(unsigned, f);
    u += 0x7FFFu + ((u >> 16) & 1u);
    return (short)(u >> 16);
}
__device__ __forceinline__ float bf2f(short h) {           // exact widen
    unsigned u = ((unsigned)(unsigned short)h) << 16;
    return __builtin_bit_cast(float, u);
}

__global__ __launch_bounds__(256) void prep_kernel(const float* __restrict__ W,
                                                   short* __restrict__ Wh,
                                                   short* __restrict__ Wl,
                                                   double* __restrict__ WdT,
                                                   int* __restrict__ count) {
    int t = blockIdx.x * 256 + threadIdx.x;   // t = e*4096 + k
    float w = W[t];
    short h = f2bf(w);
    Wh[t] = h;
    Wl[t] = f2bf(w - bf2f(h));
    int e = t >> 12, k = t & 4095;
    WdT[(size_t)k * E + e] = (double)w;
    if (t == 0) *count = 0;
}

// ---------------------------------------------------------------------------
// MFMA gate, LDS-free pure stream.  Grid 1024 x 256thr; wave = 16 rows x
// 64 experts x K/4.  4096 independent waves (16/CU), zero barriers.
// A-frags: x direct from global (row=l&15, kg=l>>4 -- layout verified r10),
// cvt to bf16 hi/lo in regs.  B-frags: Wh/Wl direct bf16x8 loads (L1/L2;
// the block's 4 waves share one W k-slice).  12 MFMA per k32:
// logits = xh*Wh + xh*Wl + xl*Wh (fp32 accum), err sigma ~1e-5.
// Partials [SPLIT][M][E] fp32 -> proven reduce epilogue.
// ---------------------------------------------------------------------------
__global__ __launch_bounds__(256) void gate_kernel(
    const float* __restrict__ x,
    const short* __restrict__ Wh,
    const short* __restrict__ Wl,
    float* __restrict__ part)
{
    const int t  = threadIdx.x;
    const int l  = t & 63;
    const int wv = t >> 6;
    const int h    = blockIdx.x & (SPLIT - 1);        // 4 waves share k-slice
    const int row0 = (blockIdx.x >> 2) * 64 + wv * 16;
    const int k0   = h * KPS;

    const int kg   = l >> 4;                          // 0..3 k-granule
    const int xrow = row0 + (l & 15);

    const float* gx = x + (size_t)xrow * K + k0 + kg * 8;
    const short* pwh[4];
    const short* pwl[4];
#pragma unroll
    for (int et = 0; et < 4; ++et) {
        const int e = et * 16 + (l & 15);
        pwh[et] = Wh + (size_t)e * K + k0 + kg * 8;
        pwl[et] = Wl + (size_t)e * K + k0 + kg * 8;
    }

    f32x4 acc[4] = {{0,0,0,0},{0,0,0,0},{0,0,0,0},{0,0,0,0}};

    for (int c = 0; c < NCH; ++c) {
        const int ko = c * 32;
        float4 xa = *reinterpret_cast<const float4*>(gx + ko);
        float4 xb = *reinterpret_cast<const float4*>(gx + ko + 4);
        float vv[8] = {xa.x, xa.y, xa.z, xa.w, xb.x, xb.y, xb.z, xb.w};
        bf16x8 ah, al;
#pragma unroll
        for (int j = 0; j < 8; ++j) {
            short hh = f2bf(vv[j]);
            ah[j] = hh;
            al[j] = f2bf(vv[j] - bf2f(hh));
        }
#pragma unroll
        for (int et = 0; et < 4; ++et) {
            bf16x8 bh = *reinterpret_cast<const bf16x8*>(pwh[et] + ko);
            bf16x8 bl = *reinterpret_cast<const bf16x8*>(pwl[et] + ko);
            acc[et] = __builtin_amdgcn_mfma_f32_16x16x32_bf16(ah, bh, acc[et], 0, 0, 0);
            acc[et] = __builtin_amdgcn_mfma_f32_16x16x32_bf16(ah, bl, acc[et], 0, 0, 0);
            acc[et] = __builtin_amdgcn_mfma_f32_16x16x32_bf16(al, bh, acc[et], 0, 0, 0);
        }
    }

    // D layout (verified r10): row = (l>>4)*4 + r (A-side), col = l&15 (B-side)
#pragma unroll
    for (int et = 0; et < 4; ++et)
#pragma unroll
        for (int r = 0; r < 4; ++r)
            part[((size_t)h * M + row0 + (l >> 4) * 4 + r) * E + et * 16 + (l & 15)]
                = acc[et][r];
}

// ---------------------------------------------------------------------------
// Reduce + top-9 + sparse softmax + ambiguity flag (proven rounds 3-9).
// ---------------------------------------------------------------------------
__global__ __launch_bounds__(256) void reduce_kernel(
    const float* __restrict__ part,
    const float* __restrict__ b,
    float* __restrict__ outp,
    float* __restrict__ outi,
    int*   __restrict__ count,
    int*   __restrict__ list)
{
    const int lane = threadIdx.x & 63;
    const int w    = threadIdx.x >> 6;
    const int row  = blockIdx.x * 4 + w;

    float orig = b[lane];
#pragma unroll
    for (int hh = 0; hh < SPLIT; ++hh)
        orig += part[((size_t)hh * M + row) * E + lane];

    float cur = orig;
    float vals[9];
    float myidxf = 0.0f;
    bool  sel = false;

#pragma unroll
    for (int i = 0; i < 9; ++i) {
        float m = cur;
#pragma unroll
        for (int off = 32; off > 0; off >>= 1)
            m = fmaxf(m, __shfl_xor(m, off, 64));
        unsigned long long msk = __ballot(cur == m);
        int il = __ffsll((long long)msk) - 1;
        vals[i] = m;
        if (lane == il) { cur = -FLT_MAX; if (i < TOPK) sel = true; }
        if (i < TOPK && lane == i) myidxf = (float)il;
    }

    float ssum = 0.0f;
#pragma unroll
    for (int i = 0; i < TOPK; ++i) ssum += expf(vals[i] - vals[0]);
    float p = sel ? (expf(orig - vals[0]) / ssum) : 0.0f;

    outp[(size_t)row * E + lane] = p;
    if (lane < TOPK) outi[(size_t)row * TOPK + lane] = myidxf;

    float mingap = FLT_MAX;
#pragma unroll
    for (int i = 0; i < 8; ++i) mingap = fminf(mingap, vals[i] - vals[i + 1]);
    if (lane == 0 && mingap < GAP_THRESH) {
        int pos = atomicAdd(count, 1);
        if (pos < M) list[pos] = row;
    }
}

// ---------------------------------------------------------------------------
// fp64 rescue, batched 3 rows/block sharing one WdT stream (proven r10).
// ---------------------------------------------------------------------------
__global__ __launch_bounds__(192) void fix_kernel(
    const float*  __restrict__ x,
    const double* __restrict__ WdT,
    const float*  __restrict__ b,
    float* __restrict__ outp,
    float* __restrict__ outi,
    const int* __restrict__ count,
    const int* __restrict__ list)
{
    __shared__ float xs[3][K];      // 48 KB
    const int l   = threadIdx.x & 63;
    const int wv  = threadIdx.x >> 6;
    const int cnt = *count;

    for (int base = blockIdx.x * 3; base < cnt; base += gridDim.x * 3) {
        const int idx = base + wv;
        const int row = (idx < cnt) ? list[idx] : list[cnt - 1];

        const float4* xr4 = reinterpret_cast<const float4*>(x + (size_t)row * K);
#pragma unroll
        for (int j = 0; j < K / 4 / 64; ++j)
            reinterpret_cast<float4*>(xs[wv])[j * 64 + l] = xr4[j * 64 + l];
        // no barrier: each wave reads only its own xs slice

        double a0 = 0.0, a1 = 0.0, a2 = 0.0, a3 = 0.0;
        for (int k = 0; k < K; k += 4) {
            float4 xv = *reinterpret_cast<const float4*>(&xs[wv][k]);
            a0 = fma((double)xv.x, WdT[(size_t)(k + 0) * E + l], a0);
            a1 = fma((double)xv.y, WdT[(size_t)(k + 1) * E + l], a1);
            a2 = fma((double)xv.z, WdT[(size_t)(k + 2) * E + l], a2);
            a3 = fma((double)xv.w, WdT[(size_t)(k + 3) * E + l], a3);
        }
        const double orig = ((a0 + a1) + (a2 + a3)) + (double)b[l];
        double cur = orig;

        double vals[TOPK];
        float  myidxf = 0.0f;
        bool   sel = false;

#pragma unroll
        for (int tt = 0; tt < TOPK; ++tt) {
            double m = cur;
#pragma unroll
            for (int off = 32; off > 0; off >>= 1) {
                double o = __shfl_xor(m, off, 64);
                m = fmax(m, o);
            }
            unsigned long long msk = __ballot(cur == m);
            int il = __ffsll((long long)msk) - 1;
            vals[tt] = m;
            if (l == il) { cur = -DBL_MAX; sel = true; }
            if (l == tt)  myidxf = (float)il;
        }

        double ssum = 0.0;
#pragma unroll
        for (int tt = 0; tt < TOPK; ++tt) ssum += exp(vals[tt] - vals[0]);
        float p = sel ? (float)(exp(orig - vals[0]) / ssum) : 0.0f;

        if (idx < cnt) {
            outp[(size_t)row * E + l] = p;
            if (l < TOPK) outi[(size_t)row * TOPK + l] = myidxf;
        }
        __syncthreads();   // xs slices reused next pass
    }
}

// ---------------------------------------------------------------------------
// Fallback (tiny ws): per-thread-row full fp64 from f32 W.  Correct, slow.
// ---------------------------------------------------------------------------
__global__ __launch_bounds__(64) void fallback_kernel(
    const float* __restrict__ x,
    const float* __restrict__ W,
    const float* __restrict__ b,
    float* __restrict__ outp,
    float* __restrict__ outi)
{
    const int row = blockIdx.x * 64 + threadIdx.x;
    double lg[64];
#pragma unroll
    for (int e = 0; e < 64; ++e) lg[e] = (double)b[e];
    const float* xr = x + (size_t)row * K;
    for (int k = 0; k < K; k += 4) {
        float4 xa = *reinterpret_cast<const float4*>(xr + k);
        double xd[4] = {(double)xa.x, (double)xa.y, (double)xa.z, (double)xa.w};
#pragma unroll
        for (int e = 0; e < 64; ++e) {
            const float* wp = W + (size_t)e * K + k;
            double a = lg[e];
#pragma unroll
            for (int j = 0; j < 4; ++j) a = fma(xd[j], (double)wp[j], a);
            lg[e] = a;
        }
    }
    unsigned long long selm = 0ull;
    double vals[TOPK]; int idx[TOPK];
#pragma unroll
    for (int i = 0; i < TOPK; ++i) {
        double m = -DBL_MAX; int mi = 0;
#pragma unroll
        for (int e = 0; e < 64; ++e) {
            bool gt = !((selm >> e) & 1ull) && (lg[e] > m);
            m = gt ? lg[e] : m; mi = gt ? e : mi;
        }
        vals[i] = m; idx[i] = mi; selm |= (1ull << mi);
    }
    double ssum = 0.0;
#pragma unroll
    for (int i = 0; i < TOPK; ++i) ssum += exp(vals[i] - vals[0]);
    double inv = 1.0 / ssum;
#pragma unroll
    for (int e = 0; e < 64; ++e)
        outp[(size_t)row * E + e] =
            ((selm >> e) & 1ull) ? (float)(exp(lg[e] - vals[0]) * inv) : 0.0f;
#pragma unroll
    for (int i = 0; i < TOPK; ++i)
        outi[(size_t)row * TOPK + i] = (float)idx[i];
}

// ---------------------------------------------------------------------------
extern "C" void kernel_launch(void* const* d_in, const int* in_sizes, int n_in,
                              void* d_out, int out_size, void* d_ws, size_t ws_size,
                              hipStream_t stream) {
    (void)in_sizes; (void)n_in; (void)out_size;
    const float* x = (const float*)d_in[0];
    const float* W = (const float*)d_in[1];
    const float* b = (const float*)d_in[2];

    float* outp = (float*)d_out;
    float* outi = outp + (size_t)M * E;

    const size_t wdt_bytes = sizeof(double) * (size_t)E * K;          // 2 MB
    const size_t wh_off    = wdt_bytes;
    const size_t wl_off    = wh_off + sizeof(short) * (size_t)E * K;  // +512 KB
    const size_t cnt_off   = wl_off + sizeof(short) * (size_t)E * K;  // +512 KB
    const size_t list_off  = cnt_off + 256;
    const size_t part_off  = list_off + (size_t)M * sizeof(int);
    const size_t need      = part_off + (size_t)SPLIT * M * E * sizeof(float);

    if (ws_size >= need) {
        double* WdT  = (double*)d_ws;
        short*  Wh   = (short*)((char*)d_ws + wh_off);
        short*  Wl   = (short*)((char*)d_ws + wl_off);
        int*    cnt  = (int*)((char*)d_ws + cnt_off);
        int*    list = (int*)((char*)d_ws + list_off);
        float*  part = (float*)((char*)d_ws + part_off);

        prep_kernel<<<(E * K) / 256, 256, 0, stream>>>(W, Wh, Wl, WdT, cnt);
        gate_kernel<<<(M / 64) * SPLIT, 256, 0, stream>>>(x, Wh, Wl, part);
        reduce_kernel<<<M / 4, 256, 0, stream>>>(part, b, outp, outi, cnt, list);
        fix_kernel<<<512, 192, 0, stream>>>(x, WdT, b, outp, outi, cnt, list);
    } else {
        fallback_kernel<<<M / 64, 64, 0, stream>>>(x, W, b, outp, outi);
    }
}

// Round 12
// 213.481 us; speedup vs baseline: 1.9706x; 1.3017x over previous
//
#include <hip/hip_runtime.h>
#include <cfloat>
#include <cmath>

#define M     16384
#define K     4096
#define E     64
#define TOPK  8
#define GAP_THRESH 3e-4f

#define SPLIT 4                 // K-split
#define KPS   (K / SPLIT)       // 1024 k per wave
#define NCH   (KPS / 32)        // 32 chunks of k32

typedef __attribute__((ext_vector_type(8))) short bf16x8;
typedef __attribute__((ext_vector_type(4))) float f32x4;

// ws layout: [WdT 2MB][Whf 512KB][Wlf 512KB][count 256B][list 64KB][part 16MB]

__device__ __forceinline__ short f2bf(float f) {           // RNE fp32->bf16
    unsigned u = __builtin_bit_cast(unsigned, f);
    u += 0x7FFFu + ((u >> 16) & 1u);
    return (short)(u >> 16);
}
__device__ __forceinline__ float bf2f(short h) {           // exact widen
    unsigned u = ((unsigned)(unsigned short)h) << 16;
    return __builtin_bit_cast(float, u);
}

// ---------------------------------------------------------------------------
// prep: split W into bf16 hi/lo stored in MFMA FRAGMENT ORDER:
//   Whf[((gc*4 + et)*64 + lane)*8 + j]  where lane = kg*16 + (e&15),
//   gc = k>>5, kg = (k&31)>>3, j = k&7, et = e>>4.
// A wave's B-frag load is then one contiguous 1KB block (was 16 scattered
// lines).  Also WdT[k][e] fp64 for the rescue, and zero the flag counter.
// ---------------------------------------------------------------------------
__global__ __launch_bounds__(256) void prep_kernel(const float* __restrict__ W,
                                                   short* __restrict__ Whf,
                                                   short* __restrict__ Wlf,
                                                   double* __restrict__ WdT,
                                                   int* __restrict__ count) {
    int t = blockIdx.x * 256 + threadIdx.x;   // t = e*4096 + k
    float w = W[t];
    short h = f2bf(w);
    short lo = f2bf(w - bf2f(h));
    int e = t >> 12, k = t & 4095;
    int gc = k >> 5, kk = k & 31;
    size_t fidx = (((size_t)gc * 4 + (e >> 4)) * 64 + (kk >> 3) * 16 + (e & 15)) * 8
                  + (kk & 7);
    Whf[fidx] = h;
    Wlf[fidx] = lo;
    WdT[(size_t)k * E + e] = (double)w;
    if (t == 0) *count = 0;
}

// ---------------------------------------------------------------------------
// MFMA gate, LDS-free, explicit 2-deep register pipeline (r11 was VGPR=28 ->
// compiler rolled the et loop -> 4 latency exposures per chunk).
// Grid 1024 x 256thr; wave = 16 rows x 64 e x K/4; 16 waves/CU, no barriers.
// A-frags: x direct (row=l&15, kg=l>>4; layout verified r10/r11), cvt hi/lo
// in regs.  B-frags: contiguous 1KB loads from fragment-ordered Whf/Wlf.
// 12 MFMA per k32: xh*Wh + xh*Wl + xl*Wh (fp32 accum, err sigma ~1e-5).
// ---------------------------------------------------------------------------
struct XW {
    float4 xa, xb;
    bf16x8 h0, h1, h2, h3, l0, l1, l2, l3;
};

__device__ __forceinline__ void load_set(XW& s, const float* gx,
                                         const short* ph, const short* pl, int cc) {
    const int ko = cc * 32;
    s.xa = *reinterpret_cast<const float4*>(gx + ko);
    s.xb = *reinterpret_cast<const float4*>(gx + ko + 4);
    const short* bh = ph + (size_t)cc * 2048;
    const short* bl = pl + (size_t)cc * 2048;
    s.h0 = *reinterpret_cast<const bf16x8*>(bh);
    s.h1 = *reinterpret_cast<const bf16x8*>(bh + 512);
    s.h2 = *reinterpret_cast<const bf16x8*>(bh + 1024);
    s.h3 = *reinterpret_cast<const bf16x8*>(bh + 1536);
    s.l0 = *reinterpret_cast<const bf16x8*>(bl);
    s.l1 = *reinterpret_cast<const bf16x8*>(bl + 512);
    s.l2 = *reinterpret_cast<const bf16x8*>(bl + 1024);
    s.l3 = *reinterpret_cast<const bf16x8*>(bl + 1536);
}

__device__ __forceinline__ void compute_set(const XW& s, f32x4 acc[4]) {
    float vv[8] = {s.xa.x, s.xa.y, s.xa.z, s.xa.w, s.xb.x, s.xb.y, s.xb.z, s.xb.w};
    bf16x8 ah, al;
#pragma unroll
    for (int j = 0; j < 8; ++j) {
        short hh = f2bf(vv[j]);
        ah[j] = hh;
        al[j] = f2bf(vv[j] - bf2f(hh));
    }
    acc[0] = __builtin_amdgcn_mfma_f32_16x16x32_bf16(ah, s.h0, acc[0], 0, 0, 0);
    acc[0] = __builtin_amdgcn_mfma_f32_16x16x32_bf16(ah, s.l0, acc[0], 0, 0, 0);
    acc[0] = __builtin_amdgcn_mfma_f32_16x16x32_bf16(al, s.h0, acc[0], 0, 0, 0);
    acc[1] = __builtin_amdgcn_mfma_f32_16x16x32_bf16(ah, s.h1, acc[1], 0, 0, 0);
    acc[1] = __builtin_amdgcn_mfma_f32_16x16x32_bf16(ah, s.l1, acc[1], 0, 0, 0);
    acc[1] = __builtin_amdgcn_mfma_f32_16x16x32_bf16(al, s.h1, acc[1], 0, 0, 0);
    acc[2] = __builtin_amdgcn_mfma_f32_16x16x32_bf16(ah, s.h2, acc[2], 0, 0, 0);
    acc[2] = __builtin_amdgcn_mfma_f32_16x16x32_bf16(ah, s.l2, acc[2], 0, 0, 0);
    acc[2] = __builtin_amdgcn_mfma_f32_16x16x32_bf16(al, s.h2, acc[2], 0, 0, 0);
    acc[3] = __builtin_amdgcn_mfma_f32_16x16x32_bf16(ah, s.h3, acc[3], 0, 0, 0);
    acc[3] = __builtin_amdgcn_mfma_f32_16x16x32_bf16(ah, s.l3, acc[3], 0, 0, 0);
    acc[3] = __builtin_amdgcn_mfma_f32_16x16x32_bf16(al, s.h3, acc[3], 0, 0, 0);
}

__global__ __launch_bounds__(256) void gate_kernel(
    const float* __restrict__ x,
    const short* __restrict__ Whf,
    const short* __restrict__ Wlf,
    float* __restrict__ part)
{
    const int t  = threadIdx.x;
    const int l  = t & 63;
    const int wv = t >> 6;
    const int h    = blockIdx.x & (SPLIT - 1);        // 4 waves share k-slice
    const int row0 = (blockIdx.x >> 2) * 64 + wv * 16;
    const int k0   = h * KPS;

    const int kg   = l >> 4;                          // 0..3 k-granule
    const int xrow = row0 + (l & 15);

    const float* gx = x + (size_t)xrow * K + k0 + kg * 8;
    // fragment-ordered W pointers for this lane & k-slice
    const short* ph = Whf + ((size_t)(k0 >> 5) * 4) * 512 + (size_t)l * 8;
    const short* pl = Wlf + ((size_t)(k0 >> 5) * 4) * 512 + (size_t)l * 8;

    f32x4 acc[4] = {{0,0,0,0},{0,0,0,0},{0,0,0,0},{0,0,0,0}};

    XW A, B;
    load_set(A, gx, ph, pl, 0);
    for (int c = 0; c < NCH; c += 2) {
        load_set(B, gx, ph, pl, c + 1);               // c+1 <= 31 always
        compute_set(A, acc);
        if (c + 2 < NCH) load_set(A, gx, ph, pl, c + 2);
        compute_set(B, acc);
    }

    // D layout (verified r10/r11): row = (l>>4)*4 + r, col = l&15
#pragma unroll
    for (int et = 0; et < 4; ++et)
#pragma unroll
        for (int r = 0; r < 4; ++r)
            part[((size_t)h * M + row0 + (l >> 4) * 4 + r) * E + et * 16 + (l & 15)]
                = acc[et][r];
}

// ---------------------------------------------------------------------------
// Reduce + top-9 + sparse softmax + ambiguity flag (proven rounds 3-11).
// ---------------------------------------------------------------------------
__global__ __launch_bounds__(256) void reduce_kernel(
    const float* __restrict__ part,
    const float* __restrict__ b,
    float* __restrict__ outp,
    float* __restrict__ outi,
    int*   __restrict__ count,
    int*   __restrict__ list)
{
    const int lane = threadIdx.x & 63;
    const int w    = threadIdx.x >> 6;
    const int row  = blockIdx.x * 4 + w;

    float orig = b[lane];
#pragma unroll
    for (int hh = 0; hh < SPLIT; ++hh)
        orig += part[((size_t)hh * M + row) * E + lane];

    float cur = orig;
    float vals[9];
    float myidxf = 0.0f;
    bool  sel = false;

#pragma unroll
    for (int i = 0; i < 9; ++i) {
        float m = cur;
#pragma unroll
        for (int off = 32; off > 0; off >>= 1)
            m = fmaxf(m, __shfl_xor(m, off, 64));
        unsigned long long msk = __ballot(cur == m);
        int il = __ffsll((long long)msk) - 1;
        vals[i] = m;
        if (lane == il) { cur = -FLT_MAX; if (i < TOPK) sel = true; }
        if (i < TOPK && lane == i) myidxf = (float)il;
    }

    float ssum = 0.0f;
#pragma unroll
    for (int i = 0; i < TOPK; ++i) ssum += expf(vals[i] - vals[0]);
    float p = sel ? (expf(orig - vals[0]) / ssum) : 0.0f;

    outp[(size_t)row * E + lane] = p;
    if (lane < TOPK) outi[(size_t)row * TOPK + lane] = myidxf;

    float mingap = FLT_MAX;
#pragma unroll
    for (int i = 0; i < 8; ++i) mingap = fminf(mingap, vals[i] - vals[i + 1]);
    if (lane == 0 && mingap < GAP_THRESH) {
        int pos = atomicAdd(count, 1);
        if (pos < M) list[pos] = row;
    }
}

// ---------------------------------------------------------------------------
// fp64 rescue, batched 3 rows/block sharing one WdT stream (proven r10/r11).
// ---------------------------------------------------------------------------
__global__ __launch_bounds__(192) void fix_kernel(
    const float*  __restrict__ x,
    const double* __restrict__ WdT,
    const float*  __restrict__ b,
    float* __restrict__ outp,
    float* __restrict__ outi,
    const int* __restrict__ count,
    const int* __restrict__ list)
{
    __shared__ float xs[3][K];      // 48 KB
    const int l   = threadIdx.x & 63;
    const int wv  = threadIdx.x >> 6;
    const int cnt = *count;

    for (int base = blockIdx.x * 3; base < cnt; base += gridDim.x * 3) {
        const int idx = base + wv;
        const int row = (idx < cnt) ? list[idx] : list[cnt - 1];

        const float4* xr4 = reinterpret_cast<const float4*>(x + (size_t)row * K);
#pragma unroll
        for (int j = 0; j < K / 4 / 64; ++j)
            reinterpret_cast<float4*>(xs[wv])[j * 64 + l] = xr4[j * 64 + l];
        // no barrier: each wave reads only its own xs slice

        double a0 = 0.0, a1 = 0.0, a2 = 0.0, a3 = 0.0;
        for (int k = 0; k < K; k += 4) {
            float4 xv = *reinterpret_cast<const float4*>(&xs[wv][k]);
            a0 = fma((double)xv.x, WdT[(size_t)(k + 0) * E + l], a0);
            a1 = fma((double)xv.y, WdT[(size_t)(k + 1) * E + l], a1);
            a2 = fma((double)xv.z, WdT[(size_t)(k + 2) * E + l], a2);
            a3 = fma((double)xv.w, WdT[(size_t)(k + 3) * E + l], a3);
        }
        const double orig = ((a0 + a1) + (a2 + a3)) + (double)b[l];
        double cur = orig;

        double vals[TOPK];
        float  myidxf = 0.0f;
        bool   sel = false;

#pragma unroll
        for (int tt = 0; tt < TOPK; ++tt) {
            double m = cur;
#pragma unroll
            for (int off = 32; off > 0; off >>= 1) {
                double o = __shfl_xor(m, off, 64);
                m = fmax(m, o);
            }
            unsigned long long msk = __ballot(cur == m);
            int il = __ffsll((long long)msk) - 1;
            vals[tt] = m;
            if (l == il) { cur = -DBL_MAX; sel = true; }
            if (l == tt)  myidxf = (float)il;
        }

        double ssum = 0.0;
#pragma unroll
        for (int tt = 0; tt < TOPK; ++tt) ssum += exp(vals[tt] - vals[0]);
        float p = sel ? (float)(exp(orig - vals[0]) / ssum) : 0.0f;

        if (idx < cnt) {
            outp[(size_t)row * E + l] = p;
            if (l < TOPK) outi[(size_t)row * TOPK + l] = myidxf;
        }
        __syncthreads();   // xs slices reused next pass
    }
}

// ---------------------------------------------------------------------------
// Fallback (tiny ws): per-thread-row full fp64 from f32 W.  Correct, slow.
// ---------------------------------------------------------------------------
__global__ __launch_bounds__(64) void fallback_kernel(
    const float* __restrict__ x,
    const float* __restrict__ W,
    const float* __restrict__ b,
    float* __restrict__ outp,
    float* __restrict__ outi)
{
    const int row = blockIdx.x * 64 + threadIdx.x;
    double lg[64];
#pragma unroll
    for (int e = 0; e < 64; ++e) lg[e] = (double)b[e];
    const float* xr = x + (size_t)row * K;
    for (int k = 0; k < K; k += 4) {
        float4 xa = *reinterpret_cast<const float4*>(xr + k);
        double xd[4] = {(double)xa.x, (double)xa.y, (double)xa.z, (double)xa.w};
#pragma unroll
        for (int e = 0; e < 64; ++e) {
            const float* wp = W + (size_t)e * K + k;
            double a = lg[e];
#pragma unroll
            for (int j = 0; j < 4; ++j) a = fma(xd[j], (double)wp[j], a);
            lg[e] = a;
        }
    }
    unsigned long long selm = 0ull;
    double vals[TOPK]; int idx[TOPK];
#pragma unroll
    for (int i = 0; i < TOPK; ++i) {
        double m = -DBL_MAX; int mi = 0;
#pragma unroll
        for (int e = 0; e < 64; ++e) {
            bool gt = !((selm >> e) & 1ull) && (lg[e] > m);
            m = gt ? lg[e] : m; mi = gt ? e : mi;
        }
        vals[i] = m; idx[i] = mi; selm |= (1ull << mi);
    }
    double ssum = 0.0;
#pragma unroll
    for (int i = 0; i < TOPK; ++i) ssum += exp(vals[i] - vals[0]);
    double inv = 1.0 / ssum;
#pragma unroll
    for (int e = 0; e < 64; ++e)
        outp[(size_t)row * E + e] =
            ((selm >> e) & 1ull) ? (float)(exp(lg[e] - vals[0]) * inv) : 0.0f;
#pragma unroll
    for (int i = 0; i < TOPK; ++i)
        outi[(size_t)row * TOPK + i] = (float)idx[i];
}

// ---------------------------------------------------------------------------
extern "C" void kernel_launch(void* const* d_in, const int* in_sizes, int n_in,
                              void* d_out, int out_size, void* d_ws, size_t ws_size,
                              hipStream_t stream) {
    (void)in_sizes; (void)n_in; (void)out_size;
    const float* x = (const float*)d_in[0];
    const float* W = (const float*)d_in[1];
    const float* b = (const float*)d_in[2];

    float* outp = (float*)d_out;
    float* outi = outp + (size_t)M * E;

    const size_t wdt_bytes = sizeof(double) * (size_t)E * K;          // 2 MB
    const size_t wh_off    = wdt_bytes;
    const size_t wl_off    = wh_off + sizeof(short) * (size_t)E * K;  // +512 KB
    const size_t cnt_off   = wl_off + sizeof(short) * (size_t)E * K;  // +512 KB
    const size_t list_off  = cnt_off + 256;
    const size_t part_off  = list_off + (size_t)M * sizeof(int);
    const size_t need      = part_off + (size_t)SPLIT * M * E * sizeof(float);

    if (ws_size >= need) {
        double* WdT  = (double*)d_ws;
        short*  Whf  = (short*)((char*)d_ws + wh_off);
        short*  Wlf  = (short*)((char*)d_ws + wl_off);
        int*    cnt  = (int*)((char*)d_ws + cnt_off);
        int*    list = (int*)((char*)d_ws + list_off);
        float*  part = (float*)((char*)d_ws + part_off);

        prep_kernel<<<(E * K) / 256, 256, 0, stream>>>(W, Whf, Wlf, WdT, cnt);
        gate_kernel<<<(M / 64) * SPLIT, 256, 0, stream>>>(x, Whf, Wlf, part);
        reduce_kernel<<<M / 4, 256, 0, stream>>>(part, b, outp, outi, cnt, list);
        fix_kernel<<<512, 192, 0, stream>>>(x, WdT, b, outp, outi, cnt, list);
    } else {
        fallback_kernel<<<M / 64, 64, 0, stream>>>(x, W, b, outp, outi);
    }
}

// Round 13
// 175.428 us; speedup vs baseline: 2.3981x; 1.2169x over previous
//
#include <hip/hip_runtime.h>
#include <cfloat>
#include <cmath>

#define M     16384
#define K     4096
#define E     64
#define TOPK  8
#define GAP_THRESH 3e-4f

#define SPLIT 4                 // K-split
#define KPS   (K / SPLIT)       // 1024 k per wave
#define NCH   (KPS / 32)        // 32 chunks of k32

typedef __attribute__((ext_vector_type(8))) short bf16x8;
typedef __attribute__((ext_vector_type(4))) float f32x4;

// ws layout: [WdT 2MB][Whf 512KB][Wlf 512KB][count 256B][list 64KB][part 16MB]

__device__ __forceinline__ short f2bf(float f) {           // RNE fp32->bf16
    unsigned u = __builtin_bit_cast(unsigned, f);
    u += 0x7FFFu + ((u >> 16) & 1u);
    return (short)(u >> 16);
}
__device__ __forceinline__ float bf2f(short h) {           // exact widen
    unsigned u = ((unsigned)(unsigned short)h) << 16;
    return __builtin_bit_cast(float, u);
}

// ---------------------------------------------------------------------------
// prep: split W into bf16 hi/lo stored in MFMA FRAGMENT ORDER (proven r12):
//   Whf[((gc*4 + et)*64 + kg*16 + (e&15))*8 + j],  gc=k>>5, kg=(k&31)>>3,
//   j=k&7, et=e>>4.  Wave B-frag load = one contiguous 1KB block.
// Also WdT[k][e] fp64 for the rescue, and zero the flag counter.
// ---------------------------------------------------------------------------
__global__ __launch_bounds__(256) void prep_kernel(const float* __restrict__ W,
                                                   short* __restrict__ Whf,
                                                   short* __restrict__ Wlf,
                                                   double* __restrict__ WdT,
                                                   int* __restrict__ count) {
    int t = blockIdx.x * 256 + threadIdx.x;   // t = e*4096 + k
    float w = W[t];
    short h = f2bf(w);
    short lo = f2bf(w - bf2f(h));
    int e = t >> 12, k = t & 4095;
    int gc = k >> 5, kk = k & 31;
    size_t fidx = (((size_t)gc * 4 + (e >> 4)) * 64 + (kk >> 3) * 16 + (e & 15)) * 8
                  + (kk & 7);
    Whf[fidx] = h;
    Wlf[fidx] = lo;
    WdT[(size_t)k * E + e] = (double)w;
    if (t == 0) *count = 0;
}

// ---------------------------------------------------------------------------
// MFMA gate (proven r12, ~26-35us): LDS-free, explicit 2-deep register
// pipeline, fragment-ordered W, 16 waves/CU, no barriers.
// ---------------------------------------------------------------------------
struct XW {
    float4 xa, xb;
    bf16x8 h0, h1, h2, h3, l0, l1, l2, l3;
};

__device__ __forceinline__ void load_set(XW& s, const float* gx,
                                         const short* ph, const short* pl, int cc) {
    const int ko = cc * 32;
    s.xa = *reinterpret_cast<const float4*>(gx + ko);
    s.xb = *reinterpret_cast<const float4*>(gx + ko + 4);
    const short* bh = ph + (size_t)cc * 2048;
    const short* bl = pl + (size_t)cc * 2048;
    s.h0 = *reinterpret_cast<const bf16x8*>(bh);
    s.h1 = *reinterpret_cast<const bf16x8*>(bh + 512);
    s.h2 = *reinterpret_cast<const bf16x8*>(bh + 1024);
    s.h3 = *reinterpret_cast<const bf16x8*>(bh + 1536);
    s.l0 = *reinterpret_cast<const bf16x8*>(bl);
    s.l1 = *reinterpret_cast<const bf16x8*>(bl + 512);
    s.l2 = *reinterpret_cast<const bf16x8*>(bl + 1024);
    s.l3 = *reinterpret_cast<const bf16x8*>(bl + 1536);
}

__device__ __forceinline__ void compute_set(const XW& s, f32x4 acc[4]) {
    float vv[8] = {s.xa.x, s.xa.y, s.xa.z, s.xa.w, s.xb.x, s.xb.y, s.xb.z, s.xb.w};
    bf16x8 ah, al;
#pragma unroll
    for (int j = 0; j < 8; ++j) {
        short hh = f2bf(vv[j]);
        ah[j] = hh;
        al[j] = f2bf(vv[j] - bf2f(hh));
    }
    acc[0] = __builtin_amdgcn_mfma_f32_16x16x32_bf16(ah, s.h0, acc[0], 0, 0, 0);
    acc[0] = __builtin_amdgcn_mfma_f32_16x16x32_bf16(ah, s.l0, acc[0], 0, 0, 0);
    acc[0] = __builtin_amdgcn_mfma_f32_16x16x32_bf16(al, s.h0, acc[0], 0, 0, 0);
    acc[1] = __builtin_amdgcn_mfma_f32_16x16x32_bf16(ah, s.h1, acc[1], 0, 0, 0);
    acc[1] = __builtin_amdgcn_mfma_f32_16x16x32_bf16(ah, s.l1, acc[1], 0, 0, 0);
    acc[1] = __builtin_amdgcn_mfma_f32_16x16x32_bf16(al, s.h1, acc[1], 0, 0, 0);
    acc[2] = __builtin_amdgcn_mfma_f32_16x16x32_bf16(ah, s.h2, acc[2], 0, 0, 0);
    acc[2] = __builtin_amdgcn_mfma_f32_16x16x32_bf16(ah, s.l2, acc[2], 0, 0, 0);
    acc[2] = __builtin_amdgcn_mfma_f32_16x16x32_bf16(al, s.h2, acc[2], 0, 0, 0);
    acc[3] = __builtin_amdgcn_mfma_f32_16x16x32_bf16(ah, s.h3, acc[3], 0, 0, 0);
    acc[3] = __builtin_amdgcn_mfma_f32_16x16x32_bf16(ah, s.l3, acc[3], 0, 0, 0);
    acc[3] = __builtin_amdgcn_mfma_f32_16x16x32_bf16(al, s.h3, acc[3], 0, 0, 0);
}

__global__ __launch_bounds__(256) void gate_kernel(
    const float* __restrict__ x,
    const short* __restrict__ Whf,
    const short* __restrict__ Wlf,
    float* __restrict__ part)
{
    const int t  = threadIdx.x;
    const int l  = t & 63;
    const int wv = t >> 6;
    const int h    = blockIdx.x & (SPLIT - 1);        // 4 waves share k-slice
    const int row0 = (blockIdx.x >> 2) * 64 + wv * 16;
    const int k0   = h * KPS;

    const int kg   = l >> 4;                          // 0..3 k-granule
    const int xrow = row0 + (l & 15);

    const float* gx = x + (size_t)xrow * K + k0 + kg * 8;
    const short* ph = Whf + ((size_t)(k0 >> 5) * 4) * 512 + (size_t)l * 8;
    const short* pl = Wlf + ((size_t)(k0 >> 5) * 4) * 512 + (size_t)l * 8;

    f32x4 acc[4] = {{0,0,0,0},{0,0,0,0},{0,0,0,0},{0,0,0,0}};

    XW A, B;
    load_set(A, gx, ph, pl, 0);
    for (int c = 0; c < NCH; c += 2) {
        load_set(B, gx, ph, pl, c + 1);
        compute_set(A, acc);
        if (c + 2 < NCH) load_set(A, gx, ph, pl, c + 2);
        compute_set(B, acc);
    }

    // D layout (verified r10-r12): row = (l>>4)*4 + r, col = l&15
#pragma unroll
    for (int et = 0; et < 4; ++et)
#pragma unroll
        for (int r = 0; r < 4; ++r)
            part[((size_t)h * M + row0 + (l >> 4) * 4 + r) * E + et * 16 + (l & 15)]
                = acc[et][r];
}

// ---------------------------------------------------------------------------
// Reduce + top-9 + sparse softmax + ambiguity flag (proven rounds 3-12).
// ---------------------------------------------------------------------------
__global__ __launch_bounds__(256) void reduce_kernel(
    const float* __restrict__ part,
    const float* __restrict__ b,
    float* __restrict__ outp,
    float* __restrict__ outi,
    int*   __restrict__ count,
    int*   __restrict__ list)
{
    const int lane = threadIdx.x & 63;
    const int w    = threadIdx.x >> 6;
    const int row  = blockIdx.x * 4 + w;

    float orig = b[lane];
#pragma unroll
    for (int hh = 0; hh < SPLIT; ++hh)
        orig += part[((size_t)hh * M + row) * E + lane];

    float cur = orig;
    float vals[9];
    float myidxf = 0.0f;
    bool  sel = false;

#pragma unroll
    for (int i = 0; i < 9; ++i) {
        float m = cur;
#pragma unroll
        for (int off = 32; off > 0; off >>= 1)
            m = fmaxf(m, __shfl_xor(m, off, 64));
        unsigned long long msk = __ballot(cur == m);
        int il = __ffsll((long long)msk) - 1;
        vals[i] = m;
        if (lane == il) { cur = -FLT_MAX; if (i < TOPK) sel = true; }
        if (i < TOPK && lane == i) myidxf = (float)il;
    }

    float ssum = 0.0f;
#pragma unroll
    for (int i = 0; i < TOPK; ++i) ssum += expf(vals[i] - vals[0]);
    float p = sel ? (expf(orig - vals[0]) / ssum) : 0.0f;

    outp[(size_t)row * E + lane] = p;
    if (lane < TOPK) outi[(size_t)row * TOPK + lane] = myidxf;

    float mingap = FLT_MAX;
#pragma unroll
    for (int i = 0; i < 8; ++i) mingap = fminf(mingap, vals[i] - vals[i + 1]);
    if (lane == 0 && mingap < GAP_THRESH) {
        int pos = atomicAdd(count, 1);
        if (pos < M) list[pos] = row;
    }
}

// ---------------------------------------------------------------------------
// fp64 rescue, r13: one row per block, the fp64 dot K-SPLIT across the
// block's 4 waves (wave w owns k in [w*1024,(w+1)*1024), lane = expert) --
// cuts the per-row serial latency chain 4x vs r12's one-row-per-wave.
// WdT loads prefetched 1-deep in named registers (rule #20).  Partials
// combined via LDS psum[4][64]; wave 0 runs the proven ballot epilogue.
// ---------------------------------------------------------------------------
__global__ __launch_bounds__(256) void fix_kernel(
    const float*  __restrict__ x,
    const double* __restrict__ WdT,
    const float*  __restrict__ b,
    float* __restrict__ outp,
    float* __restrict__ outi,
    const int* __restrict__ count,
    const int* __restrict__ list)
{
    __shared__ float  xs[K];         // 16 KB
    __shared__ double psum[4][E];    // 2 KB
    const int t   = threadIdx.x;
    const int l   = t & 63;
    const int wv  = t >> 6;
    const int cnt = *count;

    for (int i = blockIdx.x; i < cnt; i += gridDim.x) {
        const int row = list[i];

        // stage x row: 256 thr x 4 float4, coalesced
        const float4* xr4 = reinterpret_cast<const float4*>(x + (size_t)row * K);
#pragma unroll
        for (int j = 0; j < 4; ++j)
            reinterpret_cast<float4*>(xs)[j * 256 + t] = xr4[j * 256 + t];
        __syncthreads();

        const int k0 = wv << 10;                       // this wave's k-slice
        const double* wp = WdT + (size_t)k0 * E + l;

        double a0 = 0.0, a1 = 0.0, a2 = 0.0, a3 = 0.0;
        // 1-deep named-register prefetch of the 4 WdT rows
        double c0 = wp[0], c1 = wp[E], c2 = wp[2 * E], c3 = wp[3 * E];
        for (int kk = 0; kk < 1024; kk += 4) {
            double n0, n1, n2, n3;
            if (kk + 4 < 1024) {
                const double* np = wp + (size_t)(kk + 4) * E;
                n0 = np[0]; n1 = np[E]; n2 = np[2 * E]; n3 = np[3 * E];
            }
            float4 xv = *reinterpret_cast<const float4*>(xs + k0 + kk);
            a0 = fma((double)xv.x, c0, a0);
            a1 = fma((double)xv.y, c1, a1);
            a2 = fma((double)xv.z, c2, a2);
            a3 = fma((double)xv.w, c3, a3);
            c0 = n0; c1 = n1; c2 = n2; c3 = n3;
        }
        psum[wv][l] = ((a0 + a1) + (a2 + a3));
        __syncthreads();

        if (wv == 0) {
            const double orig = ((psum[0][l] + psum[1][l]) + (psum[2][l] + psum[3][l]))
                                + (double)b[l];
            double cur = orig;

            double vals[TOPK];
            float  myidxf = 0.0f;
            bool   sel = false;

#pragma unroll
            for (int tt = 0; tt < TOPK; ++tt) {
                double m = cur;
#pragma unroll
                for (int off = 32; off > 0; off >>= 1) {
                    double o = __shfl_xor(m, off, 64);
                    m = fmax(m, o);
                }
                unsigned long long msk = __ballot(cur == m);
                int il = __ffsll((long long)msk) - 1;
                vals[tt] = m;
                if (l == il) { cur = -DBL_MAX; sel = true; }
                if (l == tt)  myidxf = (float)il;
            }

            double ssum = 0.0;
#pragma unroll
            for (int tt = 0; tt < TOPK; ++tt) ssum += exp(vals[tt] - vals[0]);
            float p = sel ? (float)(exp(orig - vals[0]) / ssum) : 0.0f;

            outp[(size_t)row * E + l] = p;
            if (l < TOPK) outi[(size_t)row * TOPK + l] = myidxf;
        }
        __syncthreads();   // xs/psum reused next iteration
    }
}

// ---------------------------------------------------------------------------
// Fallback (tiny ws): per-thread-row full fp64 from f32 W.  Correct, slow.
// ---------------------------------------------------------------------------
__global__ __launch_bounds__(64) void fallback_kernel(
    const float* __restrict__ x,
    const float* __restrict__ W,
    const float* __restrict__ b,
    float* __restrict__ outp,
    float* __restrict__ outi)
{
    const int row = blockIdx.x * 64 + threadIdx.x;
    double lg[64];
#pragma unroll
    for (int e = 0; e < 64; ++e) lg[e] = (double)b[e];
    const float* xr = x + (size_t)row * K;
    for (int k = 0; k < K; k += 4) {
        float4 xa = *reinterpret_cast<const float4*>(xr + k);
        double xd[4] = {(double)xa.x, (double)xa.y, (double)xa.z, (double)xa.w};
#pragma unroll
        for (int e = 0; e < 64; ++e) {
            const float* wp = W + (size_t)e * K + k;
            double a = lg[e];
#pragma unroll
            for (int j = 0; j < 4; ++j) a = fma(xd[j], (double)wp[j], a);
            lg[e] = a;
        }
    }
    unsigned long long selm = 0ull;
    double vals[TOPK]; int idx[TOPK];
#pragma unroll
    for (int i = 0; i < TOPK; ++i) {
        double m = -DBL_MAX; int mi = 0;
#pragma unroll
        for (int e = 0; e < 64; ++e) {
            bool gt = !((selm >> e) & 1ull) && (lg[e] > m);
            m = gt ? lg[e] : m; mi = gt ? e : mi;
        }
        vals[i] = m; idx[i] = mi; selm |= (1ull << mi);
    }
    double ssum = 0.0;
#pragma unroll
    for (int i = 0; i < TOPK; ++i) ssum += exp(vals[i] - vals[0]);
    double inv = 1.0 / ssum;
#pragma unroll
    for (int e = 0; e < 64; ++e)
        outp[(size_t)row * E + e] =
            ((selm >> e) & 1ull) ? (float)(exp(lg[e] - vals[0]) * inv) : 0.0f;
#pragma unroll
    for (int i = 0; i < TOPK; ++i)
        outi[(size_t)row * TOPK + i] = (float)idx[i];
}

// ---------------------------------------------------------------------------
extern "C" void kernel_launch(void* const* d_in, const int* in_sizes, int n_in,
                              void* d_out, int out_size, void* d_ws, size_t ws_size,
                              hipStream_t stream) {
    (void)in_sizes; (void)n_in; (void)out_size;
    const float* x = (const float*)d_in[0];
    const float* W = (const float*)d_in[1];
    const float* b = (const float*)d_in[2];

    float* outp = (float*)d_out;
    float* outi = outp + (size_t)M * E;

    const size_t wdt_bytes = sizeof(double) * (size_t)E * K;          // 2 MB
    const size_t wh_off    = wdt_bytes;
    const size_t wl_off    = wh_off + sizeof(short) * (size_t)E * K;  // +512 KB
    const size_t cnt_off   = wl_off + sizeof(short) * (size_t)E * K;  // +512 KB
    const size_t list_off  = cnt_off + 256;
    const size_t part_off  = list_off + (size_t)M * sizeof(int);
    const size_t need      = part_off + (size_t)SPLIT * M * E * sizeof(float);

    if (ws_size >= need) {
        double* WdT  = (double*)d_ws;
        short*  Whf  = (short*)((char*)d_ws + wh_off);
        short*  Wlf  = (short*)((char*)d_ws + wl_off);
        int*    cnt  = (int*)((char*)d_ws + cnt_off);
        int*    list = (int*)((char*)d_ws + list_off);
        float*  part = (float*)((char*)d_ws + part_off);

        prep_kernel<<<(E * K) / 256, 256, 0, stream>>>(W, Whf, Wlf, WdT, cnt);
        gate_kernel<<<(M / 64) * SPLIT, 256, 0, stream>>>(x, Whf, Wlf, part);
        reduce_kernel<<<M / 4, 256, 0, stream>>>(part, b, outp, outi, cnt, list);
        fix_kernel<<<1024, 256, 0, stream>>>(x, WdT, b, outp, outi, cnt, list);
    } else {
        fallback_kernel<<<M / 64, 64, 0, stream>>>(x, W, b, outp, outi);
    }
}

// Round 14
// 146.124 us; speedup vs baseline: 2.8790x; 1.2005x over previous
//
#include <hip/hip_runtime.h>
#include <cfloat>
#include <cmath>

#define M     16384
#define K     4096
#define E     64
#define TOPK  8
#define GAP_THRESH 3e-4f

#define SPLIT 4                 // K-split (gate)
#define KPS   (K / SPLIT)       // 1024 k per wave
#define NCH   (KPS / 32)        // 32 chunks of k32
#define FIXR  2                 // rows per fix block

typedef __attribute__((ext_vector_type(8))) short bf16x8;
typedef __attribute__((ext_vector_type(4))) float f32x4;

// ws layout: [WdT 2MB][Whf 512KB][Wlf 512KB][count 256B][list 64KB][part 16MB]

__device__ __forceinline__ short f2bf(float f) {           // RNE fp32->bf16
    unsigned u = __builtin_bit_cast(unsigned, f);
    u += 0x7FFFu + ((u >> 16) & 1u);
    return (short)(u >> 16);
}
__device__ __forceinline__ float bf2f(short h) {           // exact widen
    unsigned u = ((unsigned)(unsigned short)h) << 16;
    return __builtin_bit_cast(float, u);
}

// ---------------------------------------------------------------------------
// prep: Whf/Wlf in MFMA fragment order (proven r12); WdT[k][e] fp64 written
// COALESCED (r13 wrote it 8B-scattered at stride 512B: 8x write amplify).
// The strided W re-read for the transpose is L2-absorbed (W = 1MB).
// ---------------------------------------------------------------------------
__global__ __launch_bounds__(256) void prep_kernel(const float* __restrict__ W,
                                                   short* __restrict__ Whf,
                                                   short* __restrict__ Wlf,
                                                   double* __restrict__ WdT,
                                                   int* __restrict__ count) {
    int t = blockIdx.x * 256 + threadIdx.x;   // t = e*4096 + k
    float w = W[t];
    short h = f2bf(w);
    short lo = f2bf(w - bf2f(h));
    int e = t >> 12, k = t & 4095;
    int gc = k >> 5, kk = k & 31;
    size_t fidx = (((size_t)gc * 4 + (e >> 4)) * 64 + (kk >> 3) * 16 + (e & 15)) * 8
                  + (kk & 7);
    Whf[fidx] = h;
    Wlf[fidx] = lo;
    // coalesced WdT write: reinterpret t as k-major (t = k2*64 + e2)
    int k2 = t >> 6, e2 = t & 63;
    WdT[t] = (double)W[(size_t)e2 * K + k2];
    if (t == 0) *count = 0;
}

// ---------------------------------------------------------------------------
// MFMA gate (proven r12/r13): LDS-free, explicit 2-deep register pipeline,
// fragment-ordered W, 16 waves/CU, no barriers.
// ---------------------------------------------------------------------------
struct XW {
    float4 xa, xb;
    bf16x8 h0, h1, h2, h3, l0, l1, l2, l3;
};

__device__ __forceinline__ void load_set(XW& s, const float* gx,
                                         const short* ph, const short* pl, int cc) {
    const int ko = cc * 32;
    s.xa = *reinterpret_cast<const float4*>(gx + ko);
    s.xb = *reinterpret_cast<const float4*>(gx + ko + 4);
    const short* bh = ph + (size_t)cc * 2048;
    const short* bl = pl + (size_t)cc * 2048;
    s.h0 = *reinterpret_cast<const bf16x8*>(bh);
    s.h1 = *reinterpret_cast<const bf16x8*>(bh + 512);
    s.h2 = *reinterpret_cast<const bf16x8*>(bh + 1024);
    s.h3 = *reinterpret_cast<const bf16x8*>(bh + 1536);
    s.l0 = *reinterpret_cast<const bf16x8*>(bl);
    s.l1 = *reinterpret_cast<const bf16x8*>(bl + 512);
    s.l2 = *reinterpret_cast<const bf16x8*>(bl + 1024);
    s.l3 = *reinterpret_cast<const bf16x8*>(bl + 1536);
}

__device__ __forceinline__ void compute_set(const XW& s, f32x4 acc[4]) {
    float vv[8] = {s.xa.x, s.xa.y, s.xa.z, s.xa.w, s.xb.x, s.xb.y, s.xb.z, s.xb.w};
    bf16x8 ah, al;
#pragma unroll
    for (int j = 0; j < 8; ++j) {
        short hh = f2bf(vv[j]);
        ah[j] = hh;
        al[j] = f2bf(vv[j] - bf2f(hh));
    }
    acc[0] = __builtin_amdgcn_mfma_f32_16x16x32_bf16(ah, s.h0, acc[0], 0, 0, 0);
    acc[0] = __builtin_amdgcn_mfma_f32_16x16x32_bf16(ah, s.l0, acc[0], 0, 0, 0);
    acc[0] = __builtin_amdgcn_mfma_f32_16x16x32_bf16(al, s.h0, acc[0], 0, 0, 0);
    acc[1] = __builtin_amdgcn_mfma_f32_16x16x32_bf16(ah, s.h1, acc[1], 0, 0, 0);
    acc[1] = __builtin_amdgcn_mfma_f32_16x16x32_bf16(ah, s.l1, acc[1], 0, 0, 0);
    acc[1] = __builtin_amdgcn_mfma_f32_16x16x32_bf16(al, s.h1, acc[1], 0, 0, 0);
    acc[2] = __builtin_amdgcn_mfma_f32_16x16x32_bf16(ah, s.h2, acc[2], 0, 0, 0);
    acc[2] = __builtin_amdgcn_mfma_f32_16x16x32_bf16(ah, s.l2, acc[2], 0, 0, 0);
    acc[2] = __builtin_amdgcn_mfma_f32_16x16x32_bf16(al, s.h2, acc[2], 0, 0, 0);
    acc[3] = __builtin_amdgcn_mfma_f32_16x16x32_bf16(ah, s.h3, acc[3], 0, 0, 0);
    acc[3] = __builtin_amdgcn_mfma_f32_16x16x32_bf16(ah, s.l3, acc[3], 0, 0, 0);
    acc[3] = __builtin_amdgcn_mfma_f32_16x16x32_bf16(al, s.h3, acc[3], 0, 0, 0);
}

__global__ __launch_bounds__(256) void gate_kernel(
    const float* __restrict__ x,
    const short* __restrict__ Whf,
    const short* __restrict__ Wlf,
    float* __restrict__ part)
{
    const int t  = threadIdx.x;
    const int l  = t & 63;
    const int wv = t >> 6;
    const int h    = blockIdx.x & (SPLIT - 1);        // 4 waves share k-slice
    const int row0 = (blockIdx.x >> 2) * 64 + wv * 16;
    const int k0   = h * KPS;

    const int kg   = l >> 4;                          // 0..3 k-granule
    const int xrow = row0 + (l & 15);

    const float* gx = x + (size_t)xrow * K + k0 + kg * 8;
    const short* ph = Whf + ((size_t)(k0 >> 5) * 4) * 512 + (size_t)l * 8;
    const short* pl = Wlf + ((size_t)(k0 >> 5) * 4) * 512 + (size_t)l * 8;

    f32x4 acc[4] = {{0,0,0,0},{0,0,0,0},{0,0,0,0},{0,0,0,0}};

    XW A, B;
    load_set(A, gx, ph, pl, 0);
    for (int c = 0; c < NCH; c += 2) {
        load_set(B, gx, ph, pl, c + 1);
        compute_set(A, acc);
        if (c + 2 < NCH) load_set(A, gx, ph, pl, c + 2);
        compute_set(B, acc);
    }

    // D layout (verified r10-r13): row = (l>>4)*4 + r, col = l&15
#pragma unroll
    for (int et = 0; et < 4; ++et)
#pragma unroll
        for (int r = 0; r < 4; ++r)
            part[((size_t)h * M + row0 + (l >> 4) * 4 + r) * E + et * 16 + (l & 15)]
                = acc[et][r];
}

// ---------------------------------------------------------------------------
// Reduce + top-9 + sparse softmax + ambiguity flag (proven rounds 3-13).
// ---------------------------------------------------------------------------
__global__ __launch_bounds__(256) void reduce_kernel(
    const float* __restrict__ part,
    const float* __restrict__ b,
    float* __restrict__ outp,
    float* __restrict__ outi,
    int*   __restrict__ count,
    int*   __restrict__ list)
{
    const int lane = threadIdx.x & 63;
    const int w    = threadIdx.x >> 6;
    const int row  = blockIdx.x * 4 + w;

    float orig = b[lane];
#pragma unroll
    for (int hh = 0; hh < SPLIT; ++hh)
        orig += part[((size_t)hh * M + row) * E + lane];

    float cur = orig;
    float vals[9];
    float myidxf = 0.0f;
    bool  sel = false;

#pragma unroll
    for (int i = 0; i < 9; ++i) {
        float m = cur;
#pragma unroll
        for (int off = 32; off > 0; off >>= 1)
            m = fmaxf(m, __shfl_xor(m, off, 64));
        unsigned long long msk = __ballot(cur == m);
        int il = __ffsll((long long)msk) - 1;
        vals[i] = m;
        if (lane == il) { cur = -FLT_MAX; if (i < TOPK) sel = true; }
        if (i < TOPK && lane == i) myidxf = (float)il;
    }

    float ssum = 0.0f;
#pragma unroll
    for (int i = 0; i < TOPK; ++i) ssum += expf(vals[i] - vals[0]);
    float p = sel ? (expf(orig - vals[0]) / ssum) : 0.0f;

    outp[(size_t)row * E + lane] = p;
    if (lane < TOPK) outi[(size_t)row * TOPK + lane] = myidxf;

    float mingap = FLT_MAX;
#pragma unroll
    for (int i = 0; i < 8; ++i) mingap = fminf(mingap, vals[i] - vals[i + 1]);
    if (lane == 0 && mingap < GAP_THRESH) {
        int pos = atomicAdd(count, 1);
        if (pos < M) list[pos] = row;
    }
}

// ---------------------------------------------------------------------------
// fp64 rescue, r14: 512 thr = 8 waves; 2 rows per block SHARE each WdT load
// (the L2 load chain is the cost -- amortize it); 8-way k-split halves the
// chain length (128 iters); UNCONDITIONAL 1-deep prefetch (r13's guarded
// prefetch serialized: wait landed at the copy, ~1300 cyc/iter).  Over-read
// past WdT end lands in Whf (valid ws).  Waves 0/1 run parallel epilogues.
// ---------------------------------------------------------------------------
__global__ __launch_bounds__(512) void fix_kernel(
    const float*  __restrict__ x,
    const double* __restrict__ WdT,
    const float*  __restrict__ b,
    float* __restrict__ outp,
    float* __restrict__ outi,
    const int* __restrict__ count,
    const int* __restrict__ list)
{
    __shared__ float  xs[FIXR][K];        // 32 KB
    __shared__ double psum[8][FIXR][E];   //  8 KB
    const int t   = threadIdx.x;
    const int l   = t & 63;
    const int wv  = t >> 6;               // 0..7
    const int cnt = *count;

    for (int base = blockIdx.x * FIXR; base < cnt; base += gridDim.x * FIXR) {
        int row[FIXR];
#pragma unroll
        for (int r = 0; r < FIXR; ++r)
            row[r] = list[min(base + r, cnt - 1)];

        // stage both rows: 2048 float4 over 512 thr = 4 each, coalesced
#pragma unroll
        for (int j = 0; j < 4; ++j) {
            const int i4 = j * 512 + t;           // 0..2047
            const int rr = i4 >> 10;              // row 0/1
            const int p4 = i4 & 1023;
            reinterpret_cast<float4*>(xs[rr])[p4] =
                reinterpret_cast<const float4*>(x + (size_t)row[rr] * K)[p4];
        }
        __syncthreads();

        const int k0 = wv << 9;                   // 512 k per wave
        const double* wp = WdT + (size_t)k0 * E + l;

        double acc[FIXR][4] = {};
        double c0 = wp[0], c1 = wp[E], c2 = wp[2 * E], c3 = wp[3 * E];
        for (int kk = 0; kk < 512; kk += 4) {
            // unconditional prefetch: in flight across this iteration's FMAs
            const double* np = wp + (size_t)(kk + 4) * E;
            double n0 = np[0], n1 = np[E], n2 = np[2 * E], n3 = np[3 * E];
#pragma unroll
            for (int r = 0; r < FIXR; ++r) {
                float4 xv = *reinterpret_cast<const float4*>(xs[r] + k0 + kk);
                acc[r][0] = fma((double)xv.x, c0, acc[r][0]);
                acc[r][1] = fma((double)xv.y, c1, acc[r][1]);
                acc[r][2] = fma((double)xv.z, c2, acc[r][2]);
                acc[r][3] = fma((double)xv.w, c3, acc[r][3]);
            }
            c0 = n0; c1 = n1; c2 = n2; c3 = n3;
        }
#pragma unroll
        for (int r = 0; r < FIXR; ++r)
            psum[wv][r][l] = (acc[r][0] + acc[r][1]) + (acc[r][2] + acc[r][3]);
        __syncthreads();

        if (wv < FIXR) {
            const int r   = wv;
            const int idx = base + r;
            double orig = (double)b[l];
#pragma unroll
            for (int w = 0; w < 8; ++w) orig += psum[w][r][l];
            double cur = orig;

            double vals[TOPK];
            float  myidxf = 0.0f;
            bool   sel = false;

#pragma unroll
            for (int tt = 0; tt < TOPK; ++tt) {
                double m = cur;
#pragma unroll
                for (int off = 32; off > 0; off >>= 1) {
                    double o = __shfl_xor(m, off, 64);
                    m = fmax(m, o);
                }
                unsigned long long msk = __ballot(cur == m);
                int il = __ffsll((long long)msk) - 1;
                vals[tt] = m;
                if (l == il) { cur = -DBL_MAX; sel = true; }
                if (l == tt)  myidxf = (float)il;
            }

            double ssum = 0.0;
#pragma unroll
            for (int tt = 0; tt < TOPK; ++tt) ssum += exp(vals[tt] - vals[0]);
            float p = sel ? (float)(exp(orig - vals[0]) / ssum) : 0.0f;

            if (idx < cnt) {
                const int rw = row[r];
                outp[(size_t)rw * E + l] = p;
                if (l < TOPK) outi[(size_t)rw * TOPK + l] = myidxf;
            }
        }
        __syncthreads();   // xs/psum reused next pass
    }
}

// ---------------------------------------------------------------------------
// Fallback (tiny ws): per-thread-row full fp64 from f32 W.  Correct, slow.
// ---------------------------------------------------------------------------
__global__ __launch_bounds__(64) void fallback_kernel(
    const float* __restrict__ x,
    const float* __restrict__ W,
    const float* __restrict__ b,
    float* __restrict__ outp,
    float* __restrict__ outi)
{
    const int row = blockIdx.x * 64 + threadIdx.x;
    double lg[64];
#pragma unroll
    for (int e = 0; e < 64; ++e) lg[e] = (double)b[e];
    const float* xr = x + (size_t)row * K;
    for (int k = 0; k < K; k += 4) {
        float4 xa = *reinterpret_cast<const float4*>(xr + k);
        double xd[4] = {(double)xa.x, (double)xa.y, (double)xa.z, (double)xa.w};
#pragma unroll
        for (int e = 0; e < 64; ++e) {
            const float* wp = W + (size_t)e * K + k;
            double a = lg[e];
#pragma unroll
            for (int j = 0; j < 4; ++j) a = fma(xd[j], (double)wp[j], a);
            lg[e] = a;
        }
    }
    unsigned long long selm = 0ull;
    double vals[TOPK]; int idx[TOPK];
#pragma unroll
    for (int i = 0; i < TOPK; ++i) {
        double m = -DBL_MAX; int mi = 0;
#pragma unroll
        for (int e = 0; e < 64; ++e) {
            bool gt = !((selm >> e) & 1ull) && (lg[e] > m);
            m = gt ? lg[e] : m; mi = gt ? e : mi;
        }
        vals[i] = m; idx[i] = mi; selm |= (1ull << mi);
    }
    double ssum = 0.0;
#pragma unroll
    for (int i = 0; i < TOPK; ++i) ssum += exp(vals[i] - vals[0]);
    double inv = 1.0 / ssum;
#pragma unroll
    for (int e = 0; e < 64; ++e)
        outp[(size_t)row * E + e] =
            ((selm >> e) & 1ull) ? (float)(exp(lg[e] - vals[0]) * inv) : 0.0f;
#pragma unroll
    for (int i = 0; i < TOPK; ++i)
        outi[(size_t)row * TOPK + i] = (float)idx[i];
}

// ---------------------------------------------------------------------------
extern "C" void kernel_launch(void* const* d_in, const int* in_sizes, int n_in,
                              void* d_out, int out_size, void* d_ws, size_t ws_size,
                              hipStream_t stream) {
    (void)in_sizes; (void)n_in; (void)out_size;
    const float* x = (const float*)d_in[0];
    const float* W = (const float*)d_in[1];
    const float* b = (const float*)d_in[2];

    float* outp = (float*)d_out;
    float* outi = outp + (size_t)M * E;

    const size_t wdt_bytes = sizeof(double) * (size_t)E * K;          // 2 MB
    const size_t wh_off    = wdt_bytes;
    const size_t wl_off    = wh_off + sizeof(short) * (size_t)E * K;  // +512 KB
    const size_t cnt_off   = wl_off + sizeof(short) * (size_t)E * K;  // +512 KB
    const size_t list_off  = cnt_off + 256;
    const size_t part_off  = list_off + (size_t)M * sizeof(int);
    const size_t need      = part_off + (size_t)SPLIT * M * E * sizeof(float);

    if (ws_size >= need) {
        double* WdT  = (double*)d_ws;
        short*  Whf  = (short*)((char*)d_ws + wh_off);
        short*  Wlf  = (short*)((char*)d_ws + wl_off);
        int*    cnt  = (int*)((char*)d_ws + cnt_off);
        int*    list = (int*)((char*)d_ws + list_off);
        float*  part = (float*)((char*)d_ws + part_off);

        prep_kernel<<<(E * K) / 256, 256, 0, stream>>>(W, Whf, Wlf, WdT, cnt);
        gate_kernel<<<(M / 64) * SPLIT, 256, 0, stream>>>(x, Whf, Wlf, part);
        reduce_kernel<<<M / 4, 256, 0, stream>>>(part, b, outp, outi, cnt, list);
        fix_kernel<<<1024, 512, 0, stream>>>(x, WdT, b, outp, outi, cnt, list);
    } else {
        fallback_kernel<<<M / 64, 64, 0, stream>>>(x, W, b, outp, outi);
    }
}